// Round 5
// baseline (1947.837 us; speedup 1.0000x reference)
//
#include <hip/hip_runtime.h>

typedef float f32x4 __attribute__((ext_vector_type(4)));
typedef int   i32x4 __attribute__((ext_vector_type(4)));

#define B_ 64
#define S_ 128
#define H_ 512
#define NBLK 256        // 4 batch-tiles x 64 i-groups (8 h-idx each)
#define GUARD_MAX (1 << 17)

// ---------------------------------------------------------------------------
// (Resubmission of round-4 — bench infra failed twice; design unmeasured.)
// gru_seq: persistent, 256 blocks x 512 thr, 115 KB LDS -> 1 block/CU, all
//   256 co-resident. block g: btile bt=g>>6 (16 batches), i-group i0=(g&63)*8.
//   SYNC (vs round-3's 64-RMW flag + 256 spinning waves serializing at IF):
//   - NO atomic RMW: per-(block,wave) MONOTONE token bar[bt][ig][wave]=s+1,
//     plain sc1 store after per-wave vmcnt(0).
//   - Waiters: 64 lanes each load one block's int4 of tokens (sc0 sc1),
//     __all-ballot. Coalesced reads, zero RMW serialization.
//   - ONE barrier per step: h_s double-buffered (stage s+1 while reading s);
//     xres double-buffered. wih streamed from L2 by x-waves (latency-
//     tolerant) to fit 48+64+3 KB LDS.
// attn_tiled: 1024 blocks = 64 b x 16 s-groups(8 s each). enc[b] staged via
//   LDS per 32-row tile for QK (8x L2 traffic cut), PV L1-warm.
// Workspace: bar[4][64][4] int = 4 KB, zeroed via hipMemsetAsync.
// ---------------------------------------------------------------------------

__device__ __forceinline__ int swzW(int k4) { return k4 ^ ((k4 >> 4) & 7); }
__device__ __forceinline__ int swzH(int r, int k4) { return k4 ^ ((r >> 1) & 7); }

__global__ __launch_bounds__(512, 2) void gru_seq(
    const int*   __restrict__ dec,   // [64][128]
    const float* __restrict__ eh,    // [64][512]
    const float* __restrict__ emb,   // [32000][512]
    const float* __restrict__ wih,   // [1536][512]
    const float* __restrict__ whh,   // [1536][512]
    const float* __restrict__ bih,   // [1536]
    const float* __restrict__ bhh,   // [1536]
    float* __restrict__ out,         // [64][128][1024]
    int*   __restrict__ bar)         // [4][64][4]
{
  __shared__ __align__(16) float whh_s[24 * 512];    // 48 KB
  __shared__ __align__(16) float h_s[2 * 16 * 512];  // 64 KB double-buffered
  __shared__ float xres[2][16][8][3];                // 3 KB

  const int tid  = threadIdx.x;
  const int wave = tid >> 6;
  const int lane = tid & 63;
  const int bp   = lane & 7;       // batch pair 0..7
  const int q    = lane >> 3;      // k-chunk 0..7 (64 floats each)
  const int bt   = blockIdx.x >> 6;
  const int ig   = blockIdx.x & 63;
  const int i0   = ig * 8;
  const int b0g  = bt * 16;
  const bool hrole = (wave < 4);
  const int ilA  = (hrole ? wave : (wave - 4)) * 2;
  const int bsel = (q >> 1) & 1, ilsel = q & 1;
  const int my_b  = 2 * bp + bsel;
  const int my_il = ilA + ilsel;
  const int my_i  = i0 + my_il;

  float4* whh4 = (float4*)whh_s;
  float4* h4   = (float4*)h_s;

  // ---- stage whh slice (24 rows) into LDS once ----
  {
    const int f4 = tid & 127, r0 = tid >> 7;
    #pragma unroll
    for (int m = 0; m < 6; ++m) {
      const int row = r0 + 4 * m;              // 0..23 = gate*8 + il
      const int g = row >> 3, il = row & 7;
      whh4[row * 128 + swzW(f4)] =
          ((const float4*)whh)[(size_t)(g * 512 + i0 + il) * 128 + f4];
    }
  }

  float b_ir = 0, b_iz = 0, b_in = 0, b_hr = 0, b_hz = 0, b_hn = 0;
  if (hrole && q < 4) {
    b_ir = bih[my_i]; b_iz = bih[512 + my_i]; b_in = bih[1024 + my_i];
    b_hr = bhh[my_i]; b_hz = bhh[512 + my_i]; b_hn = bhh[1024 + my_i];
  }

  // ---- x-side matvec for step ts (wih streamed from L2) -> xres[ts&1] ----
  auto xside = [&](int ts) {
    const int tok0 = dec[(b0g + 2 * bp)     * S_ + ts];
    const int tok1 = dec[(b0g + 2 * bp + 1) * S_ + ts];
    const float4* x0 = (const float4*)(emb + (size_t)tok0 * H_);
    const float4* x1 = (const float4*)(emb + (size_t)tok1 * H_);
    const int kq = q * 16;
    const float4* w4 = (const float4*)wih;
    const float4* wp[3][2];
    #pragma unroll
    for (int g = 0; g < 3; ++g)
      #pragma unroll
      for (int e = 0; e < 2; ++e)
        wp[g][e] = w4 + (size_t)(g * 512 + i0 + ilA + e) * 128 + kq;
    float a[2][2][3] = {};
    #pragma unroll 4
    for (int c = 0; c < 16; ++c) {
      const float4 xv0 = x0[kq + c];
      const float4 xv1 = x1[kq + c];
      #pragma unroll
      for (int g = 0; g < 3; ++g) {
        #pragma unroll
        for (int e = 0; e < 2; ++e) {
          const float4 wv = wp[g][e][c];
          a[0][e][g] = fmaf(xv0.x, wv.x, fmaf(xv0.y, wv.y,
                       fmaf(xv0.z, wv.z, fmaf(xv0.w, wv.w, a[0][e][g]))));
          a[1][e][g] = fmaf(xv1.x, wv.x, fmaf(xv1.y, wv.y,
                       fmaf(xv1.z, wv.z, fmaf(xv1.w, wv.w, a[1][e][g]))));
        }
      }
    }
    #pragma unroll
    for (int bb = 0; bb < 2; ++bb)
      #pragma unroll
      for (int e = 0; e < 2; ++e)
        #pragma unroll
        for (int g = 0; g < 3; ++g) {
          float v = a[bb][e][g];
          v += __shfl_xor(v, 8); v += __shfl_xor(v, 16); v += __shfl_xor(v, 32);
          a[bb][e][g] = v;
        }
    if (q < 4) {
      const int buf = ts & 1;
      #pragma unroll
      for (int g = 0; g < 3; ++g)
        xres[buf][my_b][my_il][g] = a[bsel][ilsel][g];
    }
  };

  // ---- prelude: h(-1)=eh into buf 0; xres[0] ----
  if (hrole) {
    const int r = tid >> 4, c0 = tid & 15;
    const float4* src = (const float4*)(eh + (size_t)(b0g + r) * H_);
    #pragma unroll
    for (int j = 0; j < 8; ++j) {
      const int k4 = c0 + 16 * j;
      h4[r * 128 + swzH(r, k4)] = src[k4];
    }
  } else {
    xside(0);
  }
  __syncthreads();

  int* mytok = bar + ((bt * 64 + ig) << 2) + wave;     // this wave's token
  const int* pollp = bar + ((bt * 64 + lane) << 2);    // lane L -> block L

  // ---- recurrence: ONE barrier per step ----
  for (int s = 0; s < S_; ++s) {
    const int cb4 = (s & 1) * 2048;        // current h buffer (float4 units)
    if (hrole) {
      const int kq = q * 16;
      const int br0 = 2 * bp, br1 = br0 + 1;
      float a[2][2][3] = {};
      #pragma unroll 4
      for (int c = 0; c < 16; ++c) {
        const int k4 = kq + c;
        const float4 hv0 = h4[cb4 + br0 * 128 + swzH(br0, k4)];
        const float4 hv1 = h4[cb4 + br1 * 128 + swzH(br1, k4)];
        const int ws = swzW(k4);
        #pragma unroll
        for (int g = 0; g < 3; ++g) {
          #pragma unroll
          for (int e = 0; e < 2; ++e) {
            const float4 wv = whh4[(g * 8 + ilA + e) * 128 + ws];
            a[0][e][g] = fmaf(hv0.x, wv.x, fmaf(hv0.y, wv.y,
                         fmaf(hv0.z, wv.z, fmaf(hv0.w, wv.w, a[0][e][g]))));
            a[1][e][g] = fmaf(hv1.x, wv.x, fmaf(hv1.y, wv.y,
                         fmaf(hv1.z, wv.z, fmaf(hv1.w, wv.w, a[1][e][g]))));
          }
        }
      }
      #pragma unroll
      for (int bb = 0; bb < 2; ++bb)
        #pragma unroll
        for (int e = 0; e < 2; ++e)
          #pragma unroll
          for (int g = 0; g < 3; ++g) {
            float v = a[bb][e][g];
            v += __shfl_xor(v, 8); v += __shfl_xor(v, 16); v += __shfl_xor(v, 32);
            a[bb][e][g] = v;
          }
      if (q < 4) {
        const int buf = s & 1;
        const float ir  = xres[buf][my_b][my_il][0] + b_ir;
        const float iz  = xres[buf][my_b][my_il][1] + b_iz;
        const float in2 = xres[buf][my_b][my_il][2] + b_in;
        const float hr = a[bsel][ilsel][0] + b_hr;
        const float hz = a[bsel][ilsel][1] + b_hz;
        const float hn = a[bsel][ilsel][2] + b_hn;
        const float rr = 1.f / (1.f + expf(-(ir + hr)));
        const float zz = 1.f / (1.f + expf(-(iz + hz)));
        const float nn = tanhf(in2 + rr * hn);
        const float hold = h_s[cb4 * 4 + my_b * 512 +
                               (swzH(my_b, my_i >> 2) << 2) + (my_i & 3)];
        const float hnew = (1.f - zz) * nn + zz * hold;
        __hip_atomic_store(out + ((size_t)(b0g + my_b) * S_ + s) * 1024 + my_i,
                           hnew, __ATOMIC_RELAXED, __HIP_MEMORY_SCOPE_AGENT);
      }
      if (s + 1 < S_) {
        // per-wave token: own h stores drained -> publish s+1 (no RMW)
        asm volatile("s_waitcnt vmcnt(0)" ::: "memory");
        if (lane == 0)
          __hip_atomic_store(mytok, s + 1, __ATOMIC_RELAXED,
                             __HIP_MEMORY_SCOPE_AGENT);
        // poll: lane L watches block L's 4 wave-tokens (coalesced int4)
        i32x4 tk;
        int g2 = 0;
        do {
          asm volatile(
              "global_load_dwordx4 %0, %1, off sc0 sc1\n\t"
              "s_waitcnt vmcnt(0)"
              : "=v"(tk) : "v"(pollp) : "memory");
        } while (!__all(tk.x > s && tk.y > s && tk.z > s && tk.w > s) &&
                 ++g2 < GUARD_MAX);
        // stage h(s) -> buffer (s+1)&1 (sc0 sc1 coalesced, fresh from IF)
        {
          const int r = tid >> 4, c0 = tid & 15;
          const float* base =
              out + ((size_t)(b0g + r) * S_ + s) * 1024 + c0 * 4;
          f32x4 t0, t1, t2, t3, t4, t5, t6, t7;
          asm volatile(
              "global_load_dwordx4 %0, %8, off sc0 sc1\n\t"
              "global_load_dwordx4 %1, %8, off offset:256 sc0 sc1\n\t"
              "global_load_dwordx4 %2, %8, off offset:512 sc0 sc1\n\t"
              "global_load_dwordx4 %3, %8, off offset:768 sc0 sc1\n\t"
              "global_load_dwordx4 %4, %8, off offset:1024 sc0 sc1\n\t"
              "global_load_dwordx4 %5, %8, off offset:1280 sc0 sc1\n\t"
              "global_load_dwordx4 %6, %8, off offset:1536 sc0 sc1\n\t"
              "global_load_dwordx4 %7, %8, off offset:1792 sc0 sc1\n\t"
              "s_waitcnt vmcnt(0)"
              : "=&v"(t0), "=&v"(t1), "=&v"(t2), "=&v"(t3),
                "=&v"(t4), "=&v"(t5), "=&v"(t6), "=&v"(t7)
              : "v"(base) : "memory");
          f32x4* hx = (f32x4*)h_s;
          const int nb4 = ((s + 1) & 1) * 2048;
          hx[nb4 + r * 128 + swzH(r, c0)]       = t0;
          hx[nb4 + r * 128 + swzH(r, c0 + 16)]  = t1;
          hx[nb4 + r * 128 + swzH(r, c0 + 32)]  = t2;
          hx[nb4 + r * 128 + swzH(r, c0 + 48)]  = t3;
          hx[nb4 + r * 128 + swzH(r, c0 + 64)]  = t4;
          hx[nb4 + r * 128 + swzH(r, c0 + 80)]  = t5;
          hx[nb4 + r * 128 + swzH(r, c0 + 96)]  = t6;
          hx[nb4 + r * 128 + swzH(r, c0 + 112)] = t7;
        }
      }
    } else if (s + 1 < S_) {
      xside(s + 1);          // overlaps the whole h chain
    }
    __syncthreads();         // single per-step barrier
  }
}

// ---------------------------------------------------------------------------
// attn_tiled: block = (b, s-group of 8). QK via LDS-staged enc tiles
// (enc[b] read ONCE per block for 8 outputs), softmax per s, PV L1-warm.
__global__ __launch_bounds__(256) void attn_tiled(
    const float* __restrict__ enc,   // [64][128][512]
    float* __restrict__ out)         // [64][128][1024]; h-half already filled
{
  __shared__ __align__(16) float enc_s[32 * 512];  // 64 KB (swizzled f4)
  __shared__ __align__(16) float hsm[8 * 512];     // 16 KB (swizzled f4)
  __shared__ float pp[8][128];                     // 4 KB

  const int tid = threadIdx.x;
  const int b  = blockIdx.x & 63;    // b -> XCD b%8 (enc[b] L2-resident)
  const int sg = blockIdx.x >> 6;    // s-group 0..15
  float4* es4  = (float4*)enc_s;
  float4* hsm4 = (float4*)hsm;

  // stage 8 h rows (out h-half; kernel-boundary coherence per round 3)
  {
    const int j = tid >> 5, il = tid & 31;
    const float4* hsrc =
        (const float4*)(out + ((size_t)b * S_ + sg * 8 + j) * 1024);
    #pragma unroll
    for (int m = 0; m < 4; ++m) {
      const int k4 = il + 32 * m;
      hsm4[j * 128 + swzW(k4)] = hsrc[k4];
    }
  }
  __syncthreads();

  // ---- QK over 4 enc tiles of 32 rows ----
  const int srl = tid >> 3, q8 = tid & 7;
  for (int T = 0; T < 4; ++T) {
    {
      const float4* esrc = (const float4*)(enc + ((size_t)b * S_ + T * 32) * H_);
      #pragma unroll
      for (int m = 0; m < 16; ++m) {
        const int idx = tid + 256 * m;
        const int row = idx >> 7, k4 = idx & 127;
        es4[row * 128 + swzW(k4)] = esrc[row * 128 + k4];
      }
    }
    __syncthreads();
    float acc[8] = {};
    #pragma unroll 4
    for (int c = 0; c < 16; ++c) {
      const int ws = swzW(q8 * 16 + c);
      const float4 ev = es4[srl * 128 + ws];
      #pragma unroll
      for (int j = 0; j < 8; ++j) {
        const float4 hv = hsm4[j * 128 + ws];
        acc[j] = fmaf(ev.x, hv.x, fmaf(ev.y, hv.y,
                 fmaf(ev.z, hv.z, fmaf(ev.w, hv.w, acc[j]))));
      }
    }
    #pragma unroll
    for (int j = 0; j < 8; ++j) {
      acc[j] += __shfl_xor(acc[j], 1);
      acc[j] += __shfl_xor(acc[j], 2);
      acc[j] += __shfl_xor(acc[j], 4);
    }
    if (q8 == 0) {
      #pragma unroll
      for (int j = 0; j < 8; ++j) pp[j][T * 32 + srl] = acc[j];
    }
    __syncthreads();
  }

  // ---- softmax per s-row (half-wave per j) ----
  {
    const int jg = tid >> 5, l = tid & 31;
    float v0 = pp[jg][l], v1 = pp[jg][l + 32],
          v2 = pp[jg][l + 64], v3 = pp[jg][l + 96];
    float mx = fmaxf(fmaxf(v0, v1), fmaxf(v2, v3));
    #pragma unroll
    for (int o = 16; o > 0; o >>= 1) mx = fmaxf(mx, __shfl_xor(mx, o));
    const float e0 = expf(v0 - mx), e1 = expf(v1 - mx),
                e2 = expf(v2 - mx), e3 = expf(v3 - mx);
    float sm = e0 + e1 + e2 + e3;
    #pragma unroll
    for (int o = 16; o > 0; o >>= 1) sm += __shfl_xor(sm, o);
    const float inv = 1.f / sm;
    pp[jg][l] = e0 * inv; pp[jg][l + 32] = e1 * inv;
    pp[jg][l + 64] = e2 * inv; pp[jg][l + 96] = e3 * inv;
  }
  __syncthreads();

  // ---- PV: thread (j, 16-wide i chunk); enc rows L1-warm across j-groups --
  {
    const int j = tid >> 5, il = tid & 31;
    const float* ecol = enc + (size_t)b * (S_ * H_) + il * 16;
    const float* prow = pp[j];
    float4 c0 = {0,0,0,0}, c1 = {0,0,0,0}, c2 = {0,0,0,0}, c3 = {0,0,0,0};
    #pragma unroll 4
    for (int sr = 0; sr < S_; ++sr) {
      const float p = prow[sr];
      const float4* er = (const float4*)(ecol + (size_t)sr * H_);
      const float4 u0 = er[0], u1 = er[1], u2 = er[2], u3 = er[3];
      c0.x = fmaf(p, u0.x, c0.x); c0.y = fmaf(p, u0.y, c0.y);
      c0.z = fmaf(p, u0.z, c0.z); c0.w = fmaf(p, u0.w, c0.w);
      c1.x = fmaf(p, u1.x, c1.x); c1.y = fmaf(p, u1.y, c1.y);
      c1.z = fmaf(p, u1.z, c1.z); c1.w = fmaf(p, u1.w, c1.w);
      c2.x = fmaf(p, u2.x, c2.x); c2.y = fmaf(p, u2.y, c2.y);
      c2.z = fmaf(p, u2.z, c2.z); c2.w = fmaf(p, u2.w, c2.w);
      c3.x = fmaf(p, u3.x, c3.x); c3.y = fmaf(p, u3.y, c3.y);
      c3.z = fmaf(p, u3.z, c3.z); c3.w = fmaf(p, u3.w, c3.w);
    }
    float4* dst = (float4*)(out + ((size_t)b * S_ + sg * 8 + j) * 1024 +
                            512 + il * 16);
    dst[0] = c0; dst[1] = c1; dst[2] = c2; dst[3] = c3;
  }
}

// ---------------------------------------------------------------------------
extern "C" void kernel_launch(void* const* d_in, const int* in_sizes, int n_in,
                              void* d_out, int out_size, void* d_ws, size_t ws_size,
                              hipStream_t stream) {
  (void)in_sizes; (void)n_in; (void)out_size; (void)ws_size;
  const int*   dec = (const int*)d_in[0];
  const float* eh  = (const float*)d_in[1];
  const float* enc = (const float*)d_in[2];
  const float* emb = (const float*)d_in[3];
  const float* wih = (const float*)d_in[4];
  const float* whh = (const float*)d_in[5];
  const float* bih = (const float*)d_in[6];
  const float* bhh = (const float*)d_in[7];
  float* out = (float*)d_out;
  int*   bar = (int*)d_ws;                                // 4 KB tokens

  hipMemsetAsync(bar, 0, NBLK * 4 * sizeof(int), stream); // monotone tokens=0
  gru_seq<<<NBLK, 512, 0, stream>>>(dec, eh, emb, wih, whh, bih, bhh, out, bar);
  attn_tiled<<<16 * B_, 256, 0, stream>>>(enc, out);
}

// Round 6
// 1463.636 us; speedup vs baseline: 1.3308x; 1.3308x over previous
//
#include <hip/hip_runtime.h>
#include <string.h>

typedef float f32x4 __attribute__((ext_vector_type(4)));

#define B_ 64
#define S_ 128
#define H_ 512
#define NBLK 256        // 4 batch-tiles x 64 i-groups (8 h-idx each)
#define GUARD_MAX (1 << 17)

// ---------------------------------------------------------------------------
// Round 6: round-3 data layout (wih+whh+xres in LDS, 2-barrier schedule, the
// measured-best base at 11.2 us/step) + sync-mechanics fixes targeting the
// ~10 us/step non-compute window:
//   - ONE monotone token per block (plain sc1 store after barrier A; barrier
//     A's per-wave vmcnt(0) already drained all h-stores). No atomic RMW.
//   - ONE poller wave per block: wave 0's 64 lanes read the btile's 64 block
//     tokens as a single coalesced 256B load (sc0 sc1), __all-ballot, then
//     publish an LDS go-word. Waves 1-3 spin on LDS (no fabric traffic).
//     Round-3 had 256 waves/btile hammering one global line + 64 RMWs.
//   - h-stores paired via __shfl_xor(.,8): 64x8B agent stores per block-step
//     instead of 256x4B (fewer IF write transactions on the drain edge).
// attn_tiled unchanged (measured ~120 us).
// Workspace: bar[256] int = 1 KB, zeroed via hipMemsetAsync.
// ---------------------------------------------------------------------------

__device__ __forceinline__ int swzW(int k4) { return k4 ^ ((k4 >> 4) & 7); }
__device__ __forceinline__ int swzH(int r, int k4) { return k4 ^ ((r >> 1) & 7); }

__global__ __launch_bounds__(512, 2) void gru_seq(
    const int*   __restrict__ dec,   // [64][128]
    const float* __restrict__ eh,    // [64][512]
    const float* __restrict__ emb,   // [32000][512]
    const float* __restrict__ wih,   // [1536][512]
    const float* __restrict__ whh,   // [1536][512]
    const float* __restrict__ bih,   // [1536]
    const float* __restrict__ bhh,   // [1536]
    float* __restrict__ out,         // [64][128][1024]
    int*   __restrict__ bar)         // [256] one token per block
{
  __shared__ __align__(16) float wih_s[24 * 512];  // 48 KB
  __shared__ __align__(16) float whh_s[24 * 512];  // 48 KB
  __shared__ __align__(16) float h_s[16 * 512];    // 32 KB
  __shared__ float xres[2][16][8][3];              // 3 KB
  __shared__ volatile int go;                      // LDS relay of poll result

  const int tid  = threadIdx.x;
  const int wave = tid >> 6;
  const int lane = tid & 63;
  const int bp   = lane & 7;       // batch pair 0..7
  const int q    = lane >> 3;      // k-chunk 0..7 (64 floats each)
  const int bt   = blockIdx.x >> 6;
  const int ig   = blockIdx.x & 63;
  const int i0   = ig * 8;
  const int b0g  = bt * 16;
  const bool hrole = (wave < 4);
  const int ilA  = (hrole ? wave : (wave - 4)) * 2;
  const int bsel = (q >> 1) & 1, ilsel = q & 1;
  const int my_b  = 2 * bp + bsel;
  const int my_il = ilA + ilsel;
  const int my_i  = i0 + my_il;

  float4* wih4 = (float4*)wih_s;
  float4* whh4 = (float4*)whh_s;
  float4* h4   = (float4*)h_s;

  if (tid == 0) go = 0;

  // ---- stage both weight slices (24+24 rows) into LDS once ----
  {
    const int f4 = tid & 127, r0 = tid >> 7;
    #pragma unroll
    for (int m = 0; m < 6; ++m) {
      const int row = r0 + 4 * m;              // 0..23 = gate*8 + il
      const int g = row >> 3, il = row & 7;
      const size_t grow = (size_t)(g * 512 + i0 + il) * 128;
      wih4[row * 128 + swzW(f4)] = ((const float4*)wih)[grow + f4];
      whh4[row * 128 + swzW(f4)] = ((const float4*)whh)[grow + f4];
    }
  }

  float b_ir = 0, b_iz = 0, b_in = 0, b_hr = 0, b_hz = 0, b_hn = 0;
  if (hrole && q < 4) {
    b_ir = bih[my_i]; b_iz = bih[512 + my_i]; b_in = bih[1024 + my_i];
    b_hr = bhh[my_i]; b_hz = bhh[512 + my_i]; b_hn = bhh[1024 + my_i];
  }

  // ---- x-side matvec for step ts (wih from LDS) -> xres[ts&1] ----
  auto xside = [&](int ts) {
    const int tok0 = dec[(b0g + 2 * bp)     * S_ + ts];
    const int tok1 = dec[(b0g + 2 * bp + 1) * S_ + ts];
    const float4* x0 = (const float4*)(emb + (size_t)tok0 * H_);
    const float4* x1 = (const float4*)(emb + (size_t)tok1 * H_);
    const int kq = q * 16;
    float a[2][2][3] = {};
    #pragma unroll 4
    for (int c = 0; c < 16; ++c) {
      const int k4 = kq + c;
      const float4 xv0 = x0[k4];
      const float4 xv1 = x1[k4];
      const int ws = swzW(k4);
      #pragma unroll
      for (int g = 0; g < 3; ++g) {
        #pragma unroll
        for (int e = 0; e < 2; ++e) {
          const float4 wv = wih4[(g * 8 + ilA + e) * 128 + ws];
          a[0][e][g] = fmaf(xv0.x, wv.x, fmaf(xv0.y, wv.y,
                       fmaf(xv0.z, wv.z, fmaf(xv0.w, wv.w, a[0][e][g]))));
          a[1][e][g] = fmaf(xv1.x, wv.x, fmaf(xv1.y, wv.y,
                       fmaf(xv1.z, wv.z, fmaf(xv1.w, wv.w, a[1][e][g]))));
        }
      }
    }
    #pragma unroll
    for (int bb = 0; bb < 2; ++bb)
      #pragma unroll
      for (int e = 0; e < 2; ++e)
        #pragma unroll
        for (int g = 0; g < 3; ++g) {
          float v = a[bb][e][g];
          v += __shfl_xor(v, 8); v += __shfl_xor(v, 16); v += __shfl_xor(v, 32);
          a[bb][e][g] = v;
        }
    if (q < 4) {
      const int buf = ts & 1;
      #pragma unroll
      for (int g = 0; g < 3; ++g)
        xres[buf][my_b][my_il][g] = a[bsel][ilsel][g];
    }
  };

  // ---- stage h(s) from out via coalesced sc0 sc1 loads -> LDS ----
  auto stage_hg = [&](int sh) {
    const int r = tid >> 4, c0 = tid & 15;    // h-wave tids 0..255
    const float* base = out + ((size_t)(b0g + r) * S_ + sh) * 1024 + c0 * 4;
    f32x4 t0, t1, t2, t3, t4, t5, t6, t7;
    asm volatile(
        "global_load_dwordx4 %0, %8, off sc0 sc1\n\t"
        "global_load_dwordx4 %1, %8, off offset:256 sc0 sc1\n\t"
        "global_load_dwordx4 %2, %8, off offset:512 sc0 sc1\n\t"
        "global_load_dwordx4 %3, %8, off offset:768 sc0 sc1\n\t"
        "global_load_dwordx4 %4, %8, off offset:1024 sc0 sc1\n\t"
        "global_load_dwordx4 %5, %8, off offset:1280 sc0 sc1\n\t"
        "global_load_dwordx4 %6, %8, off offset:1536 sc0 sc1\n\t"
        "global_load_dwordx4 %7, %8, off offset:1792 sc0 sc1\n\t"
        "s_waitcnt vmcnt(0)"
        : "=&v"(t0), "=&v"(t1), "=&v"(t2), "=&v"(t3),
          "=&v"(t4), "=&v"(t5), "=&v"(t6), "=&v"(t7)
        : "v"(base) : "memory");
    f32x4* hx = (f32x4*)h_s;
    hx[r * 128 + swzH(r, c0)]       = t0;
    hx[r * 128 + swzH(r, c0 + 16)]  = t1;
    hx[r * 128 + swzH(r, c0 + 32)]  = t2;
    hx[r * 128 + swzH(r, c0 + 48)]  = t3;
    hx[r * 128 + swzH(r, c0 + 64)]  = t4;
    hx[r * 128 + swzH(r, c0 + 80)]  = t5;
    hx[r * 128 + swzH(r, c0 + 96)]  = t6;
    hx[r * 128 + swzH(r, c0 + 112)] = t7;
  };

  __syncthreads();   // weights staged (xside(0) reads wih_s)

  // ---- prelude: h(-1)=eh into LDS; xres[0] ----
  if (hrole) {
    const int r = tid >> 4, c0 = tid & 15;
    const float4* src = (const float4*)(eh + (size_t)(b0g + r) * H_);
    #pragma unroll
    for (int j = 0; j < 8; ++j) {
      const int k4 = c0 + 16 * j;
      h4[r * 128 + swzH(r, k4)] = src[k4];
    }
  } else {
    xside(0);
  }
  __syncthreads();

  // ---- recurrence ----
  for (int s = 0; s < S_; ++s) {
    float hnew = 0.f;
    if (hrole) {
      const int kq = q * 16;
      const int br0 = 2 * bp, br1 = br0 + 1;
      float a[2][2][3] = {};
      #pragma unroll 4
      for (int c = 0; c < 16; ++c) {
        const int k4 = kq + c;
        const float4 hv0 = h4[br0 * 128 + swzH(br0, k4)];
        const float4 hv1 = h4[br1 * 128 + swzH(br1, k4)];
        const int ws = swzW(k4);
        #pragma unroll
        for (int g = 0; g < 3; ++g) {
          #pragma unroll
          for (int e = 0; e < 2; ++e) {
            const float4 wv = whh4[(g * 8 + ilA + e) * 128 + ws];
            a[0][e][g] = fmaf(hv0.x, wv.x, fmaf(hv0.y, wv.y,
                         fmaf(hv0.z, wv.z, fmaf(hv0.w, wv.w, a[0][e][g]))));
            a[1][e][g] = fmaf(hv1.x, wv.x, fmaf(hv1.y, wv.y,
                         fmaf(hv1.z, wv.z, fmaf(hv1.w, wv.w, a[1][e][g]))));
          }
        }
      }
      #pragma unroll
      for (int bb = 0; bb < 2; ++bb)
        #pragma unroll
        for (int e = 0; e < 2; ++e)
          #pragma unroll
          for (int g = 0; g < 3; ++g) {
            float v = a[bb][e][g];
            v += __shfl_xor(v, 8); v += __shfl_xor(v, 16); v += __shfl_xor(v, 32);
            a[bb][e][g] = v;
          }
      if (q < 4) {
        const int buf = s & 1;
        const float ir  = xres[buf][my_b][my_il][0] + b_ir;
        const float iz  = xres[buf][my_b][my_il][1] + b_iz;
        const float in2 = xres[buf][my_b][my_il][2] + b_in;
        const float hr = a[bsel][ilsel][0] + b_hr;
        const float hz = a[bsel][ilsel][1] + b_hz;
        const float hn = a[bsel][ilsel][2] + b_hn;
        const float rr = 1.f / (1.f + expf(-(ir + hr)));
        const float zz = 1.f / (1.f + expf(-(iz + hz)));
        const float nn = tanhf(in2 + rr * hn);
        const float hold = h_s[my_b * 512 +
                               (swzH(my_b, my_i >> 2) << 2) + (my_i & 3)];
        hnew = (1.f - zz) * nn + zz * hold;
      }
      // paired store: even-q lane writes {own, partner} as one 8B agent store
      const float hpart = __shfl_xor(hnew, 8);   // q0<-q1, q2<-q3 (same b)
      if (q < 4 && (q & 1) == 0) {
        float2 hv2 = make_float2(hnew, hpart);
        unsigned long long u; memcpy(&u, &hv2, 8);
        __hip_atomic_store(
            (unsigned long long*)(out + ((size_t)(b0g + my_b) * S_ + s) * 1024 + my_i),
            u, __ATOMIC_RELAXED, __HIP_MEMORY_SCOPE_AGENT);
      }
    } else if (s + 1 < S_) {
      xside(s + 1);   // overlaps h critical path (reads wih_s)
    }

    __syncthreads();  // A: per-wave vmcnt(0) -> all h stores at IF; xres ready

    if (s + 1 < S_) {
      if (tid == 0)
        __hip_atomic_store(bar + blockIdx.x, s + 1,
                           __ATOMIC_RELAXED, __HIP_MEMORY_SCOPE_AGENT);
      if (wave == 0) {
        // single poller: 64 lanes cover the btile's 64 block tokens (256B)
        const int* tp = bar + bt * 64 + lane;
        int tk, g2 = 0;
        do {
          asm volatile(
              "global_load_dword %0, %1, off sc0 sc1\n\t"
              "s_waitcnt vmcnt(0)"
              : "=v"(tk) : "v"(tp) : "memory");
        } while (!__all(tk > s) && ++g2 < GUARD_MAX);
        if (lane == 0) go = s + 1;               // LDS relay
      } else if (hrole) {
        int g2 = 0;
        while (go < s + 1 && ++g2 < GUARD_MAX) {}  // LDS spin, no fabric load
      }
      if (hrole) stage_hg(s);
      __syncthreads();  // B: h_s holds h(s)
    }
  }
}

// ---------------------------------------------------------------------------
// attn_tiled: block = (b, s-group of 8). QK via LDS-staged enc tiles
// (enc[b] read ONCE per block for 8 outputs), softmax per s, PV L1-warm.
__global__ __launch_bounds__(256) void attn_tiled(
    const float* __restrict__ enc,   // [64][128][512]
    float* __restrict__ out)         // [64][128][1024]; h-half already filled
{
  __shared__ __align__(16) float enc_s[32 * 512];  // 64 KB (swizzled f4)
  __shared__ __align__(16) float hsm[8 * 512];     // 16 KB (swizzled f4)
  __shared__ float pp[8][128];                     // 4 KB

  const int tid = threadIdx.x;
  const int b  = blockIdx.x & 63;    // b -> XCD b%8 (enc[b] L2-resident)
  const int sg = blockIdx.x >> 6;    // s-group 0..15
  float4* es4  = (float4*)enc_s;
  float4* hsm4 = (float4*)hsm;

  {
    const int j = tid >> 5, il = tid & 31;
    const float4* hsrc =
        (const float4*)(out + ((size_t)b * S_ + sg * 8 + j) * 1024);
    #pragma unroll
    for (int m = 0; m < 4; ++m) {
      const int k4 = il + 32 * m;
      hsm4[j * 128 + swzW(k4)] = hsrc[k4];
    }
  }
  __syncthreads();

  const int srl = tid >> 3, q8 = tid & 7;
  for (int T = 0; T < 4; ++T) {
    {
      const float4* esrc = (const float4*)(enc + ((size_t)b * S_ + T * 32) * H_);
      #pragma unroll
      for (int m = 0; m < 16; ++m) {
        const int idx = tid + 256 * m;
        const int row = idx >> 7, k4 = idx & 127;
        es4[row * 128 + swzW(k4)] = esrc[row * 128 + k4];
      }
    }
    __syncthreads();
    float acc[8] = {};
    #pragma unroll 4
    for (int c = 0; c < 16; ++c) {
      const int ws = swzW(q8 * 16 + c);
      const float4 ev = es4[srl * 128 + ws];
      #pragma unroll
      for (int j = 0; j < 8; ++j) {
        const float4 hv = hsm4[j * 128 + ws];
        acc[j] = fmaf(ev.x, hv.x, fmaf(ev.y, hv.y,
                 fmaf(ev.z, hv.z, fmaf(ev.w, hv.w, acc[j]))));
      }
    }
    #pragma unroll
    for (int j = 0; j < 8; ++j) {
      acc[j] += __shfl_xor(acc[j], 1);
      acc[j] += __shfl_xor(acc[j], 2);
      acc[j] += __shfl_xor(acc[j], 4);
    }
    if (q8 == 0) {
      #pragma unroll
      for (int j = 0; j < 8; ++j) pp[j][T * 32 + srl] = acc[j];
    }
    __syncthreads();
  }

  {
    const int jg = tid >> 5, l = tid & 31;
    float v0 = pp[jg][l], v1 = pp[jg][l + 32],
          v2 = pp[jg][l + 64], v3 = pp[jg][l + 96];
    float mx = fmaxf(fmaxf(v0, v1), fmaxf(v2, v3));
    #pragma unroll
    for (int o = 16; o > 0; o >>= 1) mx = fmaxf(mx, __shfl_xor(mx, o));
    const float e0 = expf(v0 - mx), e1 = expf(v1 - mx),
                e2 = expf(v2 - mx), e3 = expf(v3 - mx);
    float sm = e0 + e1 + e2 + e3;
    #pragma unroll
    for (int o = 16; o > 0; o >>= 1) sm += __shfl_xor(sm, o);
    const float inv = 1.f / sm;
    pp[jg][l] = e0 * inv; pp[jg][l + 32] = e1 * inv;
    pp[jg][l + 64] = e2 * inv; pp[jg][l + 96] = e3 * inv;
  }
  __syncthreads();

  {
    const int j = tid >> 5, il = tid & 31;
    const float* ecol = enc + (size_t)b * (S_ * H_) + il * 16;
    const float* prow = pp[j];
    float4 c0 = {0,0,0,0}, c1 = {0,0,0,0}, c2 = {0,0,0,0}, c3 = {0,0,0,0};
    #pragma unroll 4
    for (int sr = 0; sr < S_; ++sr) {
      const float p = prow[sr];
      const float4* er = (const float4*)(ecol + (size_t)sr * H_);
      const float4 u0 = er[0], u1 = er[1], u2 = er[2], u3 = er[3];
      c0.x = fmaf(p, u0.x, c0.x); c0.y = fmaf(p, u0.y, c0.y);
      c0.z = fmaf(p, u0.z, c0.z); c0.w = fmaf(p, u0.w, c0.w);
      c1.x = fmaf(p, u1.x, c1.x); c1.y = fmaf(p, u1.y, c1.y);
      c1.z = fmaf(p, u1.z, c1.z); c1.w = fmaf(p, u1.w, c1.w);
      c2.x = fmaf(p, u2.x, c2.x); c2.y = fmaf(p, u2.y, c2.y);
      c2.z = fmaf(p, u2.z, c2.z); c2.w = fmaf(p, u2.w, c2.w);
      c3.x = fmaf(p, u3.x, c3.x); c3.y = fmaf(p, u3.y, c3.y);
      c3.z = fmaf(p, u3.z, c3.z); c3.w = fmaf(p, u3.w, c3.w);
    }
    float4* dst = (float4*)(out + ((size_t)b * S_ + sg * 8 + j) * 1024 +
                            512 + il * 16);
    dst[0] = c0; dst[1] = c1; dst[2] = c2; dst[3] = c3;
  }
}

// ---------------------------------------------------------------------------
extern "C" void kernel_launch(void* const* d_in, const int* in_sizes, int n_in,
                              void* d_out, int out_size, void* d_ws, size_t ws_size,
                              hipStream_t stream) {
  (void)in_sizes; (void)n_in; (void)out_size; (void)ws_size;
  const int*   dec = (const int*)d_in[0];
  const float* eh  = (const float*)d_in[1];
  const float* enc = (const float*)d_in[2];
  const float* emb = (const float*)d_in[3];
  const float* wih = (const float*)d_in[4];
  const float* whh = (const float*)d_in[5];
  const float* bih = (const float*)d_in[6];
  const float* bhh = (const float*)d_in[7];
  float* out = (float*)d_out;
  int*   bar = (int*)d_ws;                                // 1 KB tokens

  hipMemsetAsync(bar, 0, NBLK * sizeof(int), stream);     // monotone tokens=0
  gru_seq<<<NBLK, 512, 0, stream>>>(dec, eh, emb, wih, whh, bih, bhh, out, bar);
  attn_tiled<<<16 * B_, 256, 0, stream>>>(enc, out);
}

// Round 7
// 1329.335 us; speedup vs baseline: 1.4653x; 1.1010x over previous
//
#include <hip/hip_runtime.h>
#include <string.h>

typedef float f32x4 __attribute__((ext_vector_type(4)));
typedef int   i32x4 __attribute__((ext_vector_type(4)));

#define B_ 64
#define S_ 128
#define H_ 512
#define NBLK 256        // 4 batch-tiles x 64 i-groups (8 h-idx each)
#define GUARD_MAX (1 << 17)

// ---------------------------------------------------------------------------
// Round 7: x-waves OFF the critical path (round-6 counters: 10.2 us/step =
// max(h-compute, xside@HBM-latency) + sync chain, because barrier A joined
// the x-waves; emb gathers are ~900cyc HBM-latency loads).
//   - NO barrier inside the h sync chain. Per-wave monotone token
//     bar[blk*4+w]=s+1 (plain sc1 store after that wave's own vmcnt(0)).
//     Poll-success implies every wave of every block finished compute
//     (their tokens are in the polled set) -> staging h_s is race-free
//     without barrier A.
//   - Wave 0 polls 64x int4 (the btile's 256 tokens, coalesced, sc0 sc1),
//     relays via LDS go-word; waves 1-3 spin on LDS.
//   - ONE __syncthreads per step at the END: x-waves have the whole step
//     (~3-4 us) to hide emb HBM latency; xres ping-pong ordering preserved
//     (h reads buf s&1 during step s, x writes buf (s+1)&1, reuse separated
//     by the end barrier).
// attn_tiled unchanged (~160 us measured).
// Workspace: bar[256][4] int = 4 KB, zeroed via hipMemsetAsync.
// ---------------------------------------------------------------------------

__device__ __forceinline__ int swzW(int k4) { return k4 ^ ((k4 >> 4) & 7); }
__device__ __forceinline__ int swzH(int r, int k4) { return k4 ^ ((r >> 1) & 7); }

__global__ __launch_bounds__(512, 2) void gru_seq(
    const int*   __restrict__ dec,   // [64][128]
    const float* __restrict__ eh,    // [64][512]
    const float* __restrict__ emb,   // [32000][512]
    const float* __restrict__ wih,   // [1536][512]
    const float* __restrict__ whh,   // [1536][512]
    const float* __restrict__ bih,   // [1536]
    const float* __restrict__ bhh,   // [1536]
    float* __restrict__ out,         // [64][128][1024]
    int*   __restrict__ bar)         // [256][4] per-(block,wave) tokens
{
  __shared__ __align__(16) float wih_s[24 * 512];  // 48 KB
  __shared__ __align__(16) float whh_s[24 * 512];  // 48 KB
  __shared__ __align__(16) float h_s[16 * 512];    // 32 KB
  __shared__ float xres[2][16][8][3];              // 3 KB
  __shared__ volatile int go;                      // LDS relay of poll result

  const int tid  = threadIdx.x;
  const int wave = tid >> 6;
  const int lane = tid & 63;
  const int bp   = lane & 7;       // batch pair 0..7
  const int q    = lane >> 3;      // k-chunk 0..7 (64 floats each)
  const int bt   = blockIdx.x >> 6;
  const int ig   = blockIdx.x & 63;
  const int i0   = ig * 8;
  const int b0g  = bt * 16;
  const bool hrole = (wave < 4);
  const int ilA  = (hrole ? wave : (wave - 4)) * 2;
  const int bsel = (q >> 1) & 1, ilsel = q & 1;
  const int my_b  = 2 * bp + bsel;
  const int my_il = ilA + ilsel;
  const int my_i  = i0 + my_il;

  float4* wih4 = (float4*)wih_s;
  float4* whh4 = (float4*)whh_s;
  float4* h4   = (float4*)h_s;

  if (tid == 0) go = 0;

  // ---- stage both weight slices (24+24 rows) into LDS once ----
  {
    const int f4 = tid & 127, r0 = tid >> 7;
    #pragma unroll
    for (int m = 0; m < 6; ++m) {
      const int row = r0 + 4 * m;              // 0..23 = gate*8 + il
      const int g = row >> 3, il = row & 7;
      const size_t grow = (size_t)(g * 512 + i0 + il) * 128;
      wih4[row * 128 + swzW(f4)] = ((const float4*)wih)[grow + f4];
      whh4[row * 128 + swzW(f4)] = ((const float4*)whh)[grow + f4];
    }
  }

  float b_ir = 0, b_iz = 0, b_in = 0, b_hr = 0, b_hz = 0, b_hn = 0;
  if (hrole && q < 4) {
    b_ir = bih[my_i]; b_iz = bih[512 + my_i]; b_in = bih[1024 + my_i];
    b_hr = bhh[my_i]; b_hz = bhh[512 + my_i]; b_hn = bhh[1024 + my_i];
  }

  // ---- x-side matvec for step ts (wih from LDS) -> xres[ts&1] ----
  auto xside = [&](int ts) {
    const int tok0 = dec[(b0g + 2 * bp)     * S_ + ts];
    const int tok1 = dec[(b0g + 2 * bp + 1) * S_ + ts];
    const float4* x0 = (const float4*)(emb + (size_t)tok0 * H_);
    const float4* x1 = (const float4*)(emb + (size_t)tok1 * H_);
    const int kq = q * 16;
    float a[2][2][3] = {};
    #pragma unroll 4
    for (int c = 0; c < 16; ++c) {
      const int k4 = kq + c;
      const float4 xv0 = x0[k4];
      const float4 xv1 = x1[k4];
      const int ws = swzW(k4);
      #pragma unroll
      for (int g = 0; g < 3; ++g) {
        #pragma unroll
        for (int e = 0; e < 2; ++e) {
          const float4 wv = wih4[(g * 8 + ilA + e) * 128 + ws];
          a[0][e][g] = fmaf(xv0.x, wv.x, fmaf(xv0.y, wv.y,
                       fmaf(xv0.z, wv.z, fmaf(xv0.w, wv.w, a[0][e][g]))));
          a[1][e][g] = fmaf(xv1.x, wv.x, fmaf(xv1.y, wv.y,
                       fmaf(xv1.z, wv.z, fmaf(xv1.w, wv.w, a[1][e][g]))));
        }
      }
    }
    #pragma unroll
    for (int bb = 0; bb < 2; ++bb)
      #pragma unroll
      for (int e = 0; e < 2; ++e)
        #pragma unroll
        for (int g = 0; g < 3; ++g) {
          float v = a[bb][e][g];
          v += __shfl_xor(v, 8); v += __shfl_xor(v, 16); v += __shfl_xor(v, 32);
          a[bb][e][g] = v;
        }
    if (q < 4) {
      const int buf = ts & 1;
      #pragma unroll
      for (int g = 0; g < 3; ++g)
        xres[buf][my_b][my_il][g] = a[bsel][ilsel][g];
    }
  };

  // ---- stage h(s) from out via coalesced sc0 sc1 loads -> LDS ----
  auto stage_hg = [&](int sh) {
    const int r = tid >> 4, c0 = tid & 15;    // h-wave tids 0..255
    const float* base = out + ((size_t)(b0g + r) * S_ + sh) * 1024 + c0 * 4;
    f32x4 t0, t1, t2, t3, t4, t5, t6, t7;
    asm volatile(
        "global_load_dwordx4 %0, %8, off sc0 sc1\n\t"
        "global_load_dwordx4 %1, %8, off offset:256 sc0 sc1\n\t"
        "global_load_dwordx4 %2, %8, off offset:512 sc0 sc1\n\t"
        "global_load_dwordx4 %3, %8, off offset:768 sc0 sc1\n\t"
        "global_load_dwordx4 %4, %8, off offset:1024 sc0 sc1\n\t"
        "global_load_dwordx4 %5, %8, off offset:1280 sc0 sc1\n\t"
        "global_load_dwordx4 %6, %8, off offset:1536 sc0 sc1\n\t"
        "global_load_dwordx4 %7, %8, off offset:1792 sc0 sc1\n\t"
        "s_waitcnt vmcnt(0)"
        : "=&v"(t0), "=&v"(t1), "=&v"(t2), "=&v"(t3),
          "=&v"(t4), "=&v"(t5), "=&v"(t6), "=&v"(t7)
        : "v"(base) : "memory");
    f32x4* hx = (f32x4*)h_s;
    hx[r * 128 + swzH(r, c0)]       = t0;
    hx[r * 128 + swzH(r, c0 + 16)]  = t1;
    hx[r * 128 + swzH(r, c0 + 32)]  = t2;
    hx[r * 128 + swzH(r, c0 + 48)]  = t3;
    hx[r * 128 + swzH(r, c0 + 64)]  = t4;
    hx[r * 128 + swzH(r, c0 + 80)]  = t5;
    hx[r * 128 + swzH(r, c0 + 96)]  = t6;
    hx[r * 128 + swzH(r, c0 + 112)] = t7;
  };

  __syncthreads();   // weights staged (xside(0) reads wih_s)

  // ---- prelude: h(-1)=eh into LDS; xres[0] ----
  if (hrole) {
    const int r = tid >> 4, c0 = tid & 15;
    const float4* src = (const float4*)(eh + (size_t)(b0g + r) * H_);
    #pragma unroll
    for (int j = 0; j < 8; ++j) {
      const int k4 = c0 + 16 * j;
      h4[r * 128 + swzH(r, k4)] = src[k4];
    }
  } else {
    xside(0);
  }
  __syncthreads();

  // ---- recurrence: no barrier inside the h chain; one barrier per step ----
  for (int s = 0; s < S_; ++s) {
    if (hrole) {
      const int kq = q * 16;
      const int br0 = 2 * bp, br1 = br0 + 1;
      float a[2][2][3] = {};
      #pragma unroll 4
      for (int c = 0; c < 16; ++c) {
        const int k4 = kq + c;
        const float4 hv0 = h4[br0 * 128 + swzH(br0, k4)];
        const float4 hv1 = h4[br1 * 128 + swzH(br1, k4)];
        const int ws = swzW(k4);
        #pragma unroll
        for (int g = 0; g < 3; ++g) {
          #pragma unroll
          for (int e = 0; e < 2; ++e) {
            const float4 wv = whh4[(g * 8 + ilA + e) * 128 + ws];
            a[0][e][g] = fmaf(hv0.x, wv.x, fmaf(hv0.y, wv.y,
                         fmaf(hv0.z, wv.z, fmaf(hv0.w, wv.w, a[0][e][g]))));
            a[1][e][g] = fmaf(hv1.x, wv.x, fmaf(hv1.y, wv.y,
                         fmaf(hv1.z, wv.z, fmaf(hv1.w, wv.w, a[1][e][g]))));
          }
        }
      }
      #pragma unroll
      for (int bb = 0; bb < 2; ++bb)
        #pragma unroll
        for (int e = 0; e < 2; ++e)
          #pragma unroll
          for (int g = 0; g < 3; ++g) {
            float v = a[bb][e][g];
            v += __shfl_xor(v, 8); v += __shfl_xor(v, 16); v += __shfl_xor(v, 32);
            a[bb][e][g] = v;
          }
      float hnew = 0.f;
      if (q < 4) {
        const int buf = s & 1;
        const float ir  = xres[buf][my_b][my_il][0] + b_ir;
        const float iz  = xres[buf][my_b][my_il][1] + b_iz;
        const float in2 = xres[buf][my_b][my_il][2] + b_in;
        const float hr = a[bsel][ilsel][0] + b_hr;
        const float hz = a[bsel][ilsel][1] + b_hz;
        const float hn = a[bsel][ilsel][2] + b_hn;
        const float rr = 1.f / (1.f + expf(-(ir + hr)));
        const float zz = 1.f / (1.f + expf(-(iz + hz)));
        const float nn = tanhf(in2 + rr * hn);
        const float hold = h_s[my_b * 512 +
                               (swzH(my_b, my_i >> 2) << 2) + (my_i & 3)];
        hnew = (1.f - zz) * nn + zz * hold;
      }
      // paired store: even-q gate lane writes {own, partner} as one 8B store
      const float hpart = __shfl_xor(hnew, 8);   // q0<-q1, q2<-q3 (same b)
      if (q < 4 && (q & 1) == 0) {
        float2 hv2 = make_float2(hnew, hpart);
        unsigned long long u; memcpy(&u, &hv2, 8);
        __hip_atomic_store(
            (unsigned long long*)(out + ((size_t)(b0g + my_b) * S_ + s) * 1024 + my_i),
            u, __ATOMIC_RELAXED, __HIP_MEMORY_SCOPE_AGENT);
      }
      if (s + 1 < S_) {
        // per-wave token after OWN stores drained (no intra-block join)
        asm volatile("s_waitcnt vmcnt(0)" ::: "memory");
        if (lane == 0)
          __hip_atomic_store(bar + (blockIdx.x << 2) + wave, s + 1,
                             __ATOMIC_RELAXED, __HIP_MEMORY_SCOPE_AGENT);
        if (wave == 0) {
          // poll: lane L covers block L's 4 wave-tokens (coalesced int4)
          const int* tp = bar + ((bt * 64 + lane) << 2);
          i32x4 tk;
          int g2 = 0;
          do {
            asm volatile(
                "global_load_dwordx4 %0, %1, off sc0 sc1\n\t"
                "s_waitcnt vmcnt(0)"
                : "=v"(tk) : "v"(tp) : "memory");
          } while (!__all(tk.x > s && tk.y > s && tk.z > s && tk.w > s) &&
                   ++g2 < GUARD_MAX);
          if (lane == 0) go = s + 1;             // LDS relay
        } else {
          int g2 = 0;
          while (go < s + 1 && ++g2 < GUARD_MAX) {}  // LDS spin
        }
        __builtin_amdgcn_sched_barrier(0);
        // poll-success => every wave of every block (incl. ours) finished
        // compute(s) => safe to overwrite h_s now.
        stage_hg(s);
      }
    } else if (s + 1 < S_) {
      xside(s + 1);   // whole step window to hide emb HBM latency
    }
    __syncthreads();  // single per-step barrier: h_s staged, xres[(s+1)&1] set
  }
}

// ---------------------------------------------------------------------------
// attn_tiled: block = (b, s-group of 8). QK via LDS-staged enc tiles
// (enc[b] read ONCE per block for 8 outputs), softmax per s, PV L1-warm.
__global__ __launch_bounds__(256) void attn_tiled(
    const float* __restrict__ enc,   // [64][128][512]
    float* __restrict__ out)         // [64][128][1024]; h-half already filled
{
  __shared__ __align__(16) float enc_s[32 * 512];  // 64 KB (swizzled f4)
  __shared__ __align__(16) float hsm[8 * 512];     // 16 KB (swizzled f4)
  __shared__ float pp[8][128];                     // 4 KB

  const int tid = threadIdx.x;
  const int b  = blockIdx.x & 63;    // b -> XCD b%8 (enc[b] L2-resident)
  const int sg = blockIdx.x >> 6;    // s-group 0..15
  float4* es4  = (float4*)enc_s;
  float4* hsm4 = (float4*)hsm;

  {
    const int j = tid >> 5, il = tid & 31;
    const float4* hsrc =
        (const float4*)(out + ((size_t)b * S_ + sg * 8 + j) * 1024);
    #pragma unroll
    for (int m = 0; m < 4; ++m) {
      const int k4 = il + 32 * m;
      hsm4[j * 128 + swzW(k4)] = hsrc[k4];
    }
  }
  __syncthreads();

  const int srl = tid >> 3, q8 = tid & 7;
  for (int T = 0; T < 4; ++T) {
    {
      const float4* esrc = (const float4*)(enc + ((size_t)b * S_ + T * 32) * H_);
      #pragma unroll
      for (int m = 0; m < 16; ++m) {
        const int idx = tid + 256 * m;
        const int row = idx >> 7, k4 = idx & 127;
        es4[row * 128 + swzW(k4)] = esrc[row * 128 + k4];
      }
    }
    __syncthreads();
    float acc[8] = {};
    #pragma unroll 4
    for (int c = 0; c < 16; ++c) {
      const int ws = swzW(q8 * 16 + c);
      const float4 ev = es4[srl * 128 + ws];
      #pragma unroll
      for (int j = 0; j < 8; ++j) {
        const float4 hv = hsm4[j * 128 + ws];
        acc[j] = fmaf(ev.x, hv.x, fmaf(ev.y, hv.y,
                 fmaf(ev.z, hv.z, fmaf(ev.w, hv.w, acc[j]))));
      }
    }
    #pragma unroll
    for (int j = 0; j < 8; ++j) {
      acc[j] += __shfl_xor(acc[j], 1);
      acc[j] += __shfl_xor(acc[j], 2);
      acc[j] += __shfl_xor(acc[j], 4);
    }
    if (q8 == 0) {
      #pragma unroll
      for (int j = 0; j < 8; ++j) pp[j][T * 32 + srl] = acc[j];
    }
    __syncthreads();
  }

  {
    const int jg = tid >> 5, l = tid & 31;
    float v0 = pp[jg][l], v1 = pp[jg][l + 32],
          v2 = pp[jg][l + 64], v3 = pp[jg][l + 96];
    float mx = fmaxf(fmaxf(v0, v1), fmaxf(v2, v3));
    #pragma unroll
    for (int o = 16; o > 0; o >>= 1) mx = fmaxf(mx, __shfl_xor(mx, o));
    const float e0 = expf(v0 - mx), e1 = expf(v1 - mx),
                e2 = expf(v2 - mx), e3 = expf(v3 - mx);
    float sm = e0 + e1 + e2 + e3;
    #pragma unroll
    for (int o = 16; o > 0; o >>= 1) sm += __shfl_xor(sm, o);
    const float inv = 1.f / sm;
    pp[jg][l] = e0 * inv; pp[jg][l + 32] = e1 * inv;
    pp[jg][l + 64] = e2 * inv; pp[jg][l + 96] = e3 * inv;
  }
  __syncthreads();

  {
    const int j = tid >> 5, il = tid & 31;
    const float* ecol = enc + (size_t)b * (S_ * H_) + il * 16;
    const float* prow = pp[j];
    float4 c0 = {0,0,0,0}, c1 = {0,0,0,0}, c2 = {0,0,0,0}, c3 = {0,0,0,0};
    #pragma unroll 4
    for (int sr = 0; sr < S_; ++sr) {
      const float p = prow[sr];
      const float4* er = (const float4*)(ecol + (size_t)sr * H_);
      const float4 u0 = er[0], u1 = er[1], u2 = er[2], u3 = er[3];
      c0.x = fmaf(p, u0.x, c0.x); c0.y = fmaf(p, u0.y, c0.y);
      c0.z = fmaf(p, u0.z, c0.z); c0.w = fmaf(p, u0.w, c0.w);
      c1.x = fmaf(p, u1.x, c1.x); c1.y = fmaf(p, u1.y, c1.y);
      c1.z = fmaf(p, u1.z, c1.z); c1.w = fmaf(p, u1.w, c1.w);
      c2.x = fmaf(p, u2.x, c2.x); c2.y = fmaf(p, u2.y, c2.y);
      c2.z = fmaf(p, u2.z, c2.z); c2.w = fmaf(p, u2.w, c2.w);
      c3.x = fmaf(p, u3.x, c3.x); c3.y = fmaf(p, u3.y, c3.y);
      c3.z = fmaf(p, u3.z, c3.z); c3.w = fmaf(p, u3.w, c3.w);
    }
    float4* dst = (float4*)(out + ((size_t)b * S_ + sg * 8 + j) * 1024 +
                            512 + il * 16);
    dst[0] = c0; dst[1] = c1; dst[2] = c2; dst[3] = c3;
  }
}

// ---------------------------------------------------------------------------
extern "C" void kernel_launch(void* const* d_in, const int* in_sizes, int n_in,
                              void* d_out, int out_size, void* d_ws, size_t ws_size,
                              hipStream_t stream) {
  (void)in_sizes; (void)n_in; (void)out_size; (void)ws_size;
  const int*   dec = (const int*)d_in[0];
  const float* eh  = (const float*)d_in[1];
  const float* enc = (const float*)d_in[2];
  const float* emb = (const float*)d_in[3];
  const float* wih = (const float*)d_in[4];
  const float* whh = (const float*)d_in[5];
  const float* bih = (const float*)d_in[6];
  const float* bhh = (const float*)d_in[7];
  float* out = (float*)d_out;
  int*   bar = (int*)d_ws;                                   // 4 KB tokens

  hipMemsetAsync(bar, 0, NBLK * 4 * sizeof(int), stream);    // tokens = 0
  gru_seq<<<NBLK, 512, 0, stream>>>(dec, eh, emb, wih, whh, bih, bhh, out, bar);
  attn_tiled<<<16 * B_, 256, 0, stream>>>(enc, out);
}